// Round 18
// baseline (371.343 us; speedup 1.0000x reference)
//
#include <hip/hip_runtime.h>
#include <cstdint>

typedef __bf16 bf16_t;
typedef __attribute__((ext_vector_type(8))) __bf16 bf16x8;
typedef __attribute__((ext_vector_type(4))) float f32x4;
typedef unsigned short ushort_t;

#define TOKENS 8192
#define DIM 1024
#define HID 4096
#define NEXP 8

// meta layout (ints): [0..7] counts, [8..15] offsets, [16..23] cursors,
// [24] nslot256, [25] nslot128, [32..71] map256, [96..167] map128

__device__ __forceinline__ void gl_lds16(const void* g, void* l) {
  __builtin_amdgcn_global_load_lds(
      (__attribute__((address_space(1))) void*)(void*)g,
      (__attribute__((address_space(3))) void*)l, 16, 0, 0);
}

__device__ __forceinline__ float gelu_fast(float x) {
  float x2 = x * x;
  float z2 = x * (1.59576912f + 0.07135482f * x2);
  float e = __expf(-z2);
  return x * __builtin_amdgcn_rcpf(1.f + e);
}

// counted-vmcnt boundary: N = outstanding staging calls allowed to remain
template <int N>
__device__ __forceinline__ void pwait() {
  __builtin_amdgcn_sched_barrier(0);
  if constexpr (N == 8) asm volatile("s_waitcnt vmcnt(8)" ::: "memory");
  else if constexpr (N == 6) asm volatile("s_waitcnt vmcnt(6)" ::: "memory");
  else if constexpr (N == 4) asm volatile("s_waitcnt vmcnt(4)" ::: "memory");
  else if constexpr (N == 3) asm volatile("s_waitcnt vmcnt(3)" ::: "memory");
  else asm volatile("s_waitcnt vmcnt(0)" ::: "memory");
  __builtin_amdgcn_sched_barrier(0);
  __builtin_amdgcn_s_barrier();
  __builtin_amdgcn_sched_barrier(0);
}

// m204 bijective XCD-chunked swizzle
__device__ __forceinline__ int xcd_chunk(int f, int nwg) {
  int q = nwg >> 3, r = nwg & 7;
  int xcd = f & 7, pos = f >> 3;
  return (xcd < r) ? (xcd * (q + 1) + pos) : (r * (q + 1) + (xcd - r) * q + pos);
}

// ---------------- prep (512 thr): w1 transpose 128x64 tiles + router 8 tok/blk ----------------
// blocks [0, 4096): w1 tcvt tiles; blocks [4096, 5120): router
__global__ __launch_bounds__(512) void prep_kernel(
    const float* __restrict__ w1, bf16_t* __restrict__ w1t,
    const float* __restrict__ x, const float* __restrict__ rw,
    const float* __restrict__ rbias, bf16_t* __restrict__ xb,
    int* __restrict__ sel, float* __restrict__ gate,
    float* __restrict__ pprob, int* __restrict__ pcnt) {
  int bid = blockIdx.x;
  int t = threadIdx.x;
  if (bid < 4096) {
    // ---- w1 transpose tile: [E][D=1024][H=4096] -> [E][H][D], tile 128x64 ----
    __shared__ float tile[128][65];
    int e = bid >> 9, xb_ = bid & 511;           // 512 tiles/expert: 8 rt x 64 ct
    const float* src = w1 + (size_t)e * DIM * HID;
    bf16_t* dst = w1t + (size_t)e * DIM * HID;
    int rt = xb_ >> 6, ct = xb_ & 63;
    int rb = rt * 128, cb = ct * 64;
    int r = t >> 2, cq = (t & 3) * 16;           // 4 thr/row x 128 rows
    const float* sp = src + (size_t)(rb + r) * HID + cb + cq;
#pragma unroll
    for (int j = 0; j < 16; j += 4) {
      float4 v = *(const float4*)(sp + j);
      tile[r][cq + j + 0] = v.x; tile[r][cq + j + 1] = v.y;
      tile[r][cq + j + 2] = v.z; tile[r][cq + j + 3] = v.w;
    }
    __syncthreads();
    int oc = t >> 3, orr = (t & 7) * 16;         // 8 thr/dst-row -> 256B segments
    ushort_t tmp[16];
#pragma unroll
    for (int j = 0; j < 16; ++j) {
      bf16_t b = (bf16_t)tile[orr + j][oc];
      tmp[j] = __builtin_bit_cast(ushort_t, b);
    }
    uint4* dp = (uint4*)(dst + (size_t)(cb + oc) * DIM + rb + orr);
    dp[0] = ((uint4*)tmp)[0];
    dp[1] = ((uint4*)tmp)[1];
  } else {
    // ---- router: 8 tokens per block ----
    __shared__ float sprob[NEXP];
    __shared__ int scnt[NEXP];
    int rblk = bid - 4096;                        // 0..1023
    int lane = t & 63, wave = t >> 6;
    if (t < NEXP) { sprob[t] = 0.f; scnt[t] = 0; }
    __syncthreads();
    int tok = rblk * 8 + wave;
    const float* xp = x + (size_t)tok * DIM + lane * 16;
    float acc[NEXP];
#pragma unroll
    for (int e = 0; e < NEXP; ++e) acc[e] = 0.f;
    ushort_t xv[16];
#pragma unroll
    for (int j = 0; j < 16; j += 4) {
      float4 v = *(const float4*)(xp + j);
      const float* wr = rw + (size_t)(lane * 16 + j) * NEXP;
      float c[4] = {v.x, v.y, v.z, v.w};
#pragma unroll
      for (int d = 0; d < 4; ++d) {
        xv[j + d] = __builtin_bit_cast(ushort_t, (bf16_t)c[d]);
#pragma unroll
        for (int e = 0; e < NEXP; ++e) acc[e] += c[d] * wr[d * NEXP + e];
      }
    }
    {
      uint4* xop = (uint4*)(xb + (size_t)tok * DIM + lane * 16);
      xop[0] = ((uint4*)xv)[0];
      xop[1] = ((uint4*)xv)[1];
    }
#pragma unroll
    for (int s = 1; s < 64; s <<= 1)
#pragma unroll
      for (int e = 0; e < NEXP; ++e) acc[e] += __shfl_xor(acc[e], s);
    if (lane == 0) {
      float lg[NEXP];
#pragma unroll
      for (int e = 0; e < NEXP; ++e) lg[e] = acc[e] + rbias[e];
      float mx = lg[0]; int am = 0;
#pragma unroll
      for (int e = 1; e < NEXP; ++e) if (lg[e] > mx) { mx = lg[e]; am = e; }
      float p[NEXP]; float se = 0.f;
#pragma unroll
      for (int e = 0; e < NEXP; ++e) { p[e] = __expf(lg[e] - mx); se += p[e]; }
      float inv = 1.f / se;
#pragma unroll
      for (int e = 0; e < NEXP; ++e) { p[e] *= inv; atomicAdd(&sprob[e], p[e]); }
      sel[tok] = am;
      gate[tok] = p[am];
      atomicAdd(&scnt[am], 1);
    }
    __syncthreads();
    if (t < NEXP) {
      pprob[rblk * NEXP + t] = sprob[t];
      pcnt[rblk * NEXP + t] = scnt[t];
    }
  }
}

// ---------------- reduce partials: counts, offsets, tile maps, aux loss ----------------
__global__ void reduce_kernel(const float* __restrict__ pprob, const int* __restrict__ pcnt,
                              int nb, int* __restrict__ meta, float* __restrict__ loss_out) {
  __shared__ float fred[256];
  __shared__ int ired[256];
  int t = threadIdx.x;
  int e = t & 7, i0 = t >> 3;
  float fs = 0.f; int is = 0;
  for (int i = i0; i < nb; i += 32) { fs += pprob[i * 8 + e]; is += pcnt[i * 8 + e]; }
  fred[t] = fs; ired[t] = is;
  __syncthreads();
  if (t < NEXP) {
    float tp = 0.f; int tc = 0;
    for (int j = 0; j < 32; ++j) { tp += fred[j * 8 + t]; tc += ired[j * 8 + t]; }
    meta[t] = tc;        // counts
    fred[t] = tp;
    meta[16 + t] = 0;    // cursors
  }
  __syncthreads();
  if (t == 0) {
    int off = 0; float loss = 0.f; int s1 = 0, s2 = 0;
    for (int q = 0; q < NEXP; ++q) {
      int c = meta[q];
      meta[8 + q] = off;                       // offsets
      int nt1 = (c + 255) >> 8;
      for (int m = 0; m < nt1; ++m) meta[32 + s1++] = (q << 16) | m;
      int nt2 = (c + 127) >> 7;
      for (int m = 0; m < nt2; ++m) meta[96 + s2++] = (q << 16) | m;
      off += c;
      loss += (fred[q] / (float)TOKENS) * ((float)c / (float)TOKENS);
    }
    meta[24] = s1;                             // nslot (BM=256)
    meta[25] = s2;                             // nslot (BM=128)
    *loss_out = loss * (float)NEXP * 0.01f;
  }
}

// ---------------- scatter token indices by expert ----------------
__global__ void scatter_kernel(const int* __restrict__ sel, int* __restrict__ meta,
                               int* __restrict__ idxl) {
  int tok = blockIdx.x * 256 + threadIdx.x;
  int lane = threadIdx.x & 63;
  int e = sel[tok];
  const int* offsets = meta + 8;
  int* cursors = meta + 16;
#pragma unroll
  for (int ex = 0; ex < NEXP; ++ex) {
    unsigned long long mask = __ballot(e == ex);
    if (e == ex) {
      int leader = __ffsll(mask) - 1;
      int total = __popcll(mask);
      int rank = __popcll(mask & ((1ull << lane) - 1ull));
      int base = 0;
      if (lane == leader) base = atomicAdd(&cursors[ex], total);
      base = __shfl(base, leader);
      idxl[offsets[ex] + base + rank] = tok;
    }
  }
}

// ======== GEMM1 core (R17-proven): 256x256 tile, BK=32, 8 waves, 4-buf depth-3 ========
#define STG1(Q, KT) do {                                                     \
    int _kb = (KT) * 32;                                                     \
    gl_lds16(apA0 + _kb, L + (Q) * 16384 + wave * 512);                      \
    gl_lds16(apA1 + _kb, L + (Q) * 16384 + 4096 + wave * 512);               \
    gl_lds16(bpB0 + _kb, L + (Q) * 16384 + 8192 + wave * 512);               \
    gl_lds16(bpB1 + _kb, L + (Q) * 16384 + 12288 + wave * 512);              \
  } while (0)

#define CMP1(Q) do {                                                         \
    const bf16_t* Ab = L + (Q) * 16384;                                      \
    const bf16_t* Bb = Ab + 8192;                                            \
    bf16x8 bv[4];                                                            \
    _Pragma("unroll")                                                        \
    for (int n = 0; n < 4; ++n)                                              \
      bv[n] = *(const bf16x8*)&Bb[(wcol * 64 + n * 16 + l15) * 32 + ks];     \
    __builtin_amdgcn_s_setprio(1);                                           \
    _Pragma("unroll")                                                        \
    for (int m = 0; m < 8; ++m) {                                            \
      bf16x8 af = *(const bf16x8*)&Ab[(wrow * 128 + m * 16 + l15) * 32 + ks];\
      _Pragma("unroll")                                                      \
      for (int n = 0; n < 4; ++n)                                            \
        acc[m][n] = __builtin_amdgcn_mfma_f32_16x16x32_bf16(af, bv[n], acc[m][n], 0, 0, 0); \
    }                                                                        \
    __builtin_amdgcn_s_setprio(0);                                           \
  } while (0)

#define PIPE1(NT) do {                                                       \
    STG1(0, 0); STG1(1, 1); STG1(2, 2);                                      \
    pwait<8>();                                                              \
    _Pragma("unroll 1")                                                      \
    for (int kt = 0; kt < (NT) - 4; kt += 4) {                               \
      STG1(3, kt + 3); CMP1(0); pwait<8>();                                  \
      STG1(0, kt + 4); CMP1(1); pwait<8>();                                  \
      STG1(1, kt + 5); CMP1(2); pwait<8>();                                  \
      STG1(2, kt + 6); CMP1(3); pwait<8>();                                  \
    }                                                                        \
    STG1(3, (NT) - 1); CMP1(0); pwait<8>();                                  \
    CMP1(1); pwait<4>();                                                     \
    CMP1(2); pwait<0>();                                                     \
    CMP1(3);                                                                 \
  } while (0)

// ---------------- GEMM1 (+ fused w2 transpose blocks): 256x256 ----------------
#define G1_NWG 640    // 40 slots x 16 n-tiles
#define W2_NBLK 4096  // w2 transpose tiles (128x64), 512 thr

__global__ __launch_bounds__(512, 2) void gemm1_kernel(
    const bf16_t* __restrict__ xb, const bf16_t* __restrict__ w1t,
    const float* __restrict__ b1, const int* __restrict__ idxl,
    const int* __restrict__ meta, bf16_t* __restrict__ h,
    const float* __restrict__ w2, bf16_t* __restrict__ w2t) {
  __shared__ __align__(16) char smemraw[131072];  // 128 KB union
  int f = blockIdx.x;
  int t = threadIdx.x;

  if (f >= G1_NWG) {
    // ---- fused w2 transpose: [E][H=4096][D=1024] -> [E][D][H], tile 128x64 ----
    float (*tile)[65] = (float(*)[65])smemraw;
    int tb = f - G1_NWG;                          // 0..4095
    int e = tb >> 9, xb_ = tb & 511;              // 512 tiles/expert: 32 rt x 16 ct
    const float* src = w2 + (size_t)e * HID * DIM;
    bf16_t* dst = w2t + (size_t)e * HID * DIM;
    int rt = xb_ >> 4, ct = xb_ & 15;
    int rb = rt * 128, cb = ct * 64;
    int r = t >> 2, cq = (t & 3) * 16;
    const float* sp = src + (size_t)(rb + r) * DIM + cb + cq;
#pragma unroll
    for (int j = 0; j < 16; j += 4) {
      float4 v = *(const float4*)(sp + j);
      tile[r][cq + j + 0] = v.x; tile[r][cq + j + 1] = v.y;
      tile[r][cq + j + 2] = v.z; tile[r][cq + j + 3] = v.w;
    }
    __syncthreads();
    int oc = t >> 3, orr = (t & 7) * 16;
    ushort_t tmp[16];
#pragma unroll
    for (int j = 0; j < 16; ++j) {
      bf16_t b = (bf16_t)tile[orr + j][oc];
      tmp[j] = __builtin_bit_cast(ushort_t, b);
    }
    uint4* dp = (uint4*)(dst + (size_t)(cb + oc) * HID + rb + orr);
    dp[0] = ((uint4*)tmp)[0];
    dp[1] = ((uint4*)tmp)[1];
    return;
  }

  // ---- GEMM1 block: 256x256 ----
  bf16_t* L = (bf16_t*)smemraw;
  int lf = xcd_chunk(f, G1_NWG);
  int slot = lf % 40, nt = lf / 40;
  if (slot >= meta[24]) return;
  int tm = meta[32 + slot];
  int e = tm >> 16, mt = tm & 0xffff;
  int cnt = meta[e];
  int off = meta[8 + e];
  int mBase = mt * 256;
  int nBase = nt * 256;
  int lane = t & 63, wave = t >> 6;  // 8 waves
  int l15 = lane & 15, g = lane >> 4;
  int wrow = wave >> 2, wcol = wave & 3;  // wave tile 128x64
  int ks = (g ^ (l15 & 3)) * 8;
  f32x4 acc[8][4];
#pragma unroll
  for (int m = 0; m < 8; ++m)
#pragma unroll
    for (int n = 0; n < 4; ++n) acc[m][n] = (f32x4){0.f, 0.f, 0.f, 0.f};

  int srow = t >> 2;                       // 0..127
  int koff = ((t & 3) ^ (srow & 3)) * 8;
  int c1 = cnt - 1;
  int sA0 = mBase + srow; sA0 = sA0 < c1 ? sA0 : c1;
  int sA1 = mBase + 128 + srow; sA1 = sA1 < c1 ? sA1 : c1;
  const bf16_t* apA0 = xb + (size_t)idxl[off + sA0] * DIM + koff;
  const bf16_t* apA1 = xb + (size_t)idxl[off + sA1] * DIM + koff;
  const bf16_t* wb = w1t + (size_t)e * HID * DIM;
  const bf16_t* bpB0 = wb + (size_t)(nBase + srow) * DIM + koff;
  const bf16_t* bpB1 = wb + (size_t)(nBase + 128 + srow) * DIM + koff;

  PIPE1(32);   // K = 1024

  float bias[4];
#pragma unroll
  for (int n = 0; n < 4; ++n) bias[n] = b1[e * HID + nBase + wcol * 64 + n * 16 + l15];
#pragma unroll
  for (int m = 0; m < 8; ++m) {
    int rb0 = mBase + wrow * 128 + m * 16 + g * 4;
#pragma unroll
    for (int j = 0; j < 4; ++j) {
      int r = rb0 + j;
      if (r < cnt) {
        bf16_t* hp = h + (size_t)(off + r) * HID + nBase + wcol * 64 + l15;
#pragma unroll
        for (int n = 0; n < 4; ++n)
          hp[n * 16] = (bf16_t)gelu_fast(acc[m][n][j] + bias[n]);
      }
    }
  }
}

// ======== GEMM2: 256x128 tile, BK=32, 8 waves, 4x24KB buffers, 3-call stages ========
// Buffer (12288 elems): A 256x32 @0, B 128x32 @8192. 320 blocks -> all CUs busy.
#define STG2(Q, KT) do {                                                     \
    int _kb = (KT) * 32;                                                     \
    gl_lds16(apA0 + _kb, L + (Q) * 12288 + wave * 512);                      \
    gl_lds16(apA1 + _kb, L + (Q) * 12288 + 4096 + wave * 512);               \
    gl_lds16(bpB0 + _kb, L + (Q) * 12288 + 8192 + wave * 512);               \
  } while (0)

#define CMP2(Q) do {                                                         \
    const bf16_t* Ab = L + (Q) * 12288;                                      \
    const bf16_t* Bb = Ab + 8192;                                            \
    bf16x8 af[4], bv[4];                                                     \
    _Pragma("unroll")                                                        \
    for (int m = 0; m < 4; ++m)                                              \
      af[m] = *(const bf16x8*)&Ab[(wrow * 64 + m * 16 + l15) * 32 + ks];     \
    _Pragma("unroll")                                                        \
    for (int n = 0; n < 4; ++n)                                              \
      bv[n] = *(const bf16x8*)&Bb[(wcol * 64 + n * 16 + l15) * 32 + ks];     \
    __builtin_amdgcn_s_setprio(1);                                           \
    _Pragma("unroll")                                                        \
    for (int m = 0; m < 4; ++m)                                              \
      _Pragma("unroll")                                                      \
      for (int n = 0; n < 4; ++n)                                            \
        acc[m][n] = __builtin_amdgcn_mfma_f32_16x16x32_bf16(af[m], bv[n], acc[m][n], 0, 0, 0); \
    __builtin_amdgcn_s_setprio(0);                                           \
  } while (0)

#define PIPE2(NT) do {                                                       \
    STG2(0, 0); STG2(1, 1); STG2(2, 2);                                      \
    pwait<6>();                                                              \
    _Pragma("unroll 1")                                                      \
    for (int kt = 0; kt < (NT) - 4; kt += 4) {                               \
      STG2(3, kt + 3); CMP2(0); pwait<6>();                                  \
      STG2(0, kt + 4); CMP2(1); pwait<6>();                                  \
      STG2(1, kt + 5); CMP2(2); pwait<6>();                                  \
      STG2(2, kt + 6); CMP2(3); pwait<6>();                                  \
    }                                                                        \
    STG2(3, (NT) - 1); CMP2(0); pwait<6>();                                  \
    CMP2(1); pwait<3>();                                                     \
    CMP2(2); pwait<0>();                                                     \
    CMP2(3);                                                                 \
  } while (0)

__global__ __launch_bounds__(512, 2) void gemm2_kernel(
    const bf16_t* __restrict__ h, const bf16_t* __restrict__ w2t,
    const float* __restrict__ b2, const int* __restrict__ idxl,
    const float* __restrict__ gate, const int* __restrict__ meta,
    float* __restrict__ out) {
  __shared__ bf16_t L[49152];  // 96 KB
  int S = gridDim.x;
  int f = blockIdx.y * S + blockIdx.x;
  int lf = xcd_chunk(f, S * gridDim.y);
  int slot = lf % S, nt = lf / S;
  if (slot >= meta[24]) return;
  int tm = meta[32 + slot];
  int e = tm >> 16, mt = tm & 0xffff;
  int cnt = meta[e];
  int off = meta[8 + e];
  int mBase = mt * 256;
  int nBase = nt * 128;
  int t = threadIdx.x, lane = t & 63, wave = t >> 6;  // 8 waves
  int l15 = lane & 15, g = lane >> 4;
  int wrow = wave >> 1, wcol = wave & 1;  // wave tile 64x64 over 256x128
  int ks = (g ^ (l15 & 3)) * 8;
  f32x4 acc[4][4];
#pragma unroll
  for (int m = 0; m < 4; ++m)
#pragma unroll
    for (int n = 0; n < 4; ++n) acc[m][n] = (f32x4){0.f, 0.f, 0.f, 0.f};

  int srow = t >> 2;                       // 0..127
  int koff = ((t & 3) ^ (srow & 3)) * 8;
  int c1 = cnt - 1;
  int sA0 = mBase + srow; sA0 = sA0 < c1 ? sA0 : c1;
  int sA1 = mBase + 128 + srow; sA1 = sA1 < c1 ? sA1 : c1;
  const bf16_t* apA0 = h + (size_t)(off + sA0) * HID + koff;
  const bf16_t* apA1 = h + (size_t)(off + sA1) * HID + koff;
  const bf16_t* wb = w2t + (size_t)e * DIM * HID;
  const bf16_t* bpB0 = wb + (size_t)(nBase + srow) * HID + koff;

  PIPE2(128);  // K = 4096

  float bias[4];
#pragma unroll
  for (int n = 0; n < 4; ++n) bias[n] = b2[e * DIM + nBase + wcol * 64 + n * 16 + l15];
#pragma unroll
  for (int m = 0; m < 4; ++m) {
    int rb0 = mBase + wrow * 64 + m * 16 + g * 4;
#pragma unroll
    for (int j = 0; j < 4; ++j) {
      int r = rb0 + j;
      if (r < cnt) {
        int tok = idxl[off + r];
        float gg = gate[tok];
        float* op = out + (size_t)tok * DIM + nBase + wcol * 64 + l15;
#pragma unroll
        for (int n = 0; n < 4; ++n)
          op[n * 16] = gg * (acc[m][n][j] + bias[n]);
      }
    }
  }
}

extern "C" void kernel_launch(void* const* d_in, const int* in_sizes, int n_in,
                              void* d_out, int out_size, void* d_ws, size_t ws_size,
                              hipStream_t stream) {
  const float* hs = (const float*)d_in[0];
  const float* rw = (const float*)d_in[1];
  const float* rb = (const float*)d_in[2];
  const float* w1 = (const float*)d_in[3];
  const float* b1 = (const float*)d_in[4];
  const float* w2 = (const float*)d_in[5];
  const float* b2 = (const float*)d_in[6];
  float* out = (float*)d_out;
  char* ws = (char*)d_ws;

  // workspace layout (bytes)
  bf16_t* xb   = (bf16_t*)(ws + 0);            // 8192*1024*2       = 16,777,216
  bf16_t* w1t  = (bf16_t*)(ws + 16777216);     // 8*4096*1024*2     = 67,108,864
  bf16_t* w2t  = (bf16_t*)(ws + 83886080);     // 8*1024*4096*2     = 67,108,864
  bf16_t* hbuf = (bf16_t*)(ws + 150994944);    // (8192+256)*4096*2
  int*   sel   = (int*)  (ws + 220200960);
  float* gate  = (float*)(ws + 220233728);
  int*   idxl  = (int*)  (ws + 220266496);
  float* pprob = (float*)(ws + 220299264);
  int*   pcnt  = (int*)  (ws + 220364800);
  int*   meta  = (int*)  (ws + 220430336);     // 256 ints

  prep_kernel<<<5120, 512, 0, stream>>>(w1, w1t, hs, rw, rb, xb,
                                        sel, gate, pprob, pcnt);
  reduce_kernel<<<1, 256, 0, stream>>>(pprob, pcnt, 1024, meta, out + (out_size - 1));
  scatter_kernel<<<32, 256, 0, stream>>>(sel, meta, idxl);
  gemm1_kernel<<<G1_NWG + W2_NBLK, 512, 0, stream>>>(xb, w1t, b1, idxl, meta, hbuf,
                                                     w2, w2t);
  gemm2_kernel<<<dim3(40, 8), 512, 0, stream>>>(hbuf, w2t, b2, idxl, gate, meta, out);
}

// Round 19
// 357.716 us; speedup vs baseline: 1.0381x; 1.0381x over previous
//
#include <hip/hip_runtime.h>
#include <cstdint>

typedef __bf16 bf16_t;
typedef __attribute__((ext_vector_type(8))) __bf16 bf16x8;
typedef __attribute__((ext_vector_type(4))) float f32x4;
typedef unsigned short ushort_t;

#define TOKENS 8192
#define DIM 1024
#define HID 4096
#define NEXP 8

// meta layout (ints): [0..7] counts, [8..15] offsets, [16..23] cursors,
// [24] nslot256, [25] nslot128, [32..71] map256, [96..167] map128

__device__ __forceinline__ void gl_lds16(const void* g, void* l) {
  __builtin_amdgcn_global_load_lds(
      (__attribute__((address_space(1))) void*)(void*)g,
      (__attribute__((address_space(3))) void*)l, 16, 0, 0);
}

__device__ __forceinline__ float gelu_fast(float x) {
  float x2 = x * x;
  float z2 = x * (1.59576912f + 0.07135482f * x2);
  float e = __expf(-z2);
  return x * __builtin_amdgcn_rcpf(1.f + e);
}

// counted-vmcnt boundary: N = outstanding staging calls allowed to remain
template <int N>
__device__ __forceinline__ void pwait() {
  __builtin_amdgcn_sched_barrier(0);
  if constexpr (N == 8) asm volatile("s_waitcnt vmcnt(8)" ::: "memory");
  else if constexpr (N == 4) asm volatile("s_waitcnt vmcnt(4)" ::: "memory");
  else asm volatile("s_waitcnt vmcnt(0)" ::: "memory");
  __builtin_amdgcn_sched_barrier(0);
  __builtin_amdgcn_s_barrier();
  __builtin_amdgcn_sched_barrier(0);
}

// m204 bijective XCD-chunked swizzle
__device__ __forceinline__ int xcd_chunk(int f, int nwg) {
  int q = nwg >> 3, r = nwg & 7;
  int xcd = f & 7, pos = f >> 3;
  return (xcd < r) ? (xcd * (q + 1) + pos) : (r * (q + 1) + (xcd - r) * q + pos);
}

// ---------------- prep (512 thr): w1 transpose 128x64 tiles + router 8 tok/blk ----------------
// blocks [0, 4096): w1 tcvt tiles; blocks [4096, 5120): router
__global__ __launch_bounds__(512) void prep_kernel(
    const float* __restrict__ w1, bf16_t* __restrict__ w1t,
    const float* __restrict__ x, const float* __restrict__ rw,
    const float* __restrict__ rbias, bf16_t* __restrict__ xb,
    int* __restrict__ sel, float* __restrict__ gate,
    float* __restrict__ pprob, int* __restrict__ pcnt) {
  int bid = blockIdx.x;
  int t = threadIdx.x;
  if (bid < 4096) {
    // ---- w1 transpose tile: [E][D=1024][H=4096] -> [E][H][D], tile 128x64 ----
    __shared__ float tile[128][65];
    int e = bid >> 9, xb_ = bid & 511;           // 512 tiles/expert: 8 rt x 64 ct
    const float* src = w1 + (size_t)e * DIM * HID;
    bf16_t* dst = w1t + (size_t)e * DIM * HID;
    int rt = xb_ >> 6, ct = xb_ & 63;
    int rb = rt * 128, cb = ct * 64;
    int r = t >> 2, cq = (t & 3) * 16;           // 4 thr/row x 128 rows
    const float* sp = src + (size_t)(rb + r) * HID + cb + cq;
#pragma unroll
    for (int j = 0; j < 16; j += 4) {
      float4 v = *(const float4*)(sp + j);
      tile[r][cq + j + 0] = v.x; tile[r][cq + j + 1] = v.y;
      tile[r][cq + j + 2] = v.z; tile[r][cq + j + 3] = v.w;
    }
    __syncthreads();
    int oc = t >> 3, orr = (t & 7) * 16;         // 8 thr/dst-row -> 256B segments
    ushort_t tmp[16];
#pragma unroll
    for (int j = 0; j < 16; ++j) {
      bf16_t b = (bf16_t)tile[orr + j][oc];
      tmp[j] = __builtin_bit_cast(ushort_t, b);
    }
    uint4* dp = (uint4*)(dst + (size_t)(cb + oc) * DIM + rb + orr);
    dp[0] = ((uint4*)tmp)[0];
    dp[1] = ((uint4*)tmp)[1];
  } else {
    // ---- router: 8 tokens per block ----
    __shared__ float sprob[NEXP];
    __shared__ int scnt[NEXP];
    int rblk = bid - 4096;                        // 0..1023
    int lane = t & 63, wave = t >> 6;
    if (t < NEXP) { sprob[t] = 0.f; scnt[t] = 0; }
    __syncthreads();
    int tok = rblk * 8 + wave;
    const float* xp = x + (size_t)tok * DIM + lane * 16;
    float acc[NEXP];
#pragma unroll
    for (int e = 0; e < NEXP; ++e) acc[e] = 0.f;
    ushort_t xv[16];
#pragma unroll
    for (int j = 0; j < 16; j += 4) {
      float4 v = *(const float4*)(xp + j);
      const float* wr = rw + (size_t)(lane * 16 + j) * NEXP;
      float c[4] = {v.x, v.y, v.z, v.w};
#pragma unroll
      for (int d = 0; d < 4; ++d) {
        xv[j + d] = __builtin_bit_cast(ushort_t, (bf16_t)c[d]);
#pragma unroll
        for (int e = 0; e < NEXP; ++e) acc[e] += c[d] * wr[d * NEXP + e];
      }
    }
    {
      uint4* xop = (uint4*)(xb + (size_t)tok * DIM + lane * 16);
      xop[0] = ((uint4*)xv)[0];
      xop[1] = ((uint4*)xv)[1];
    }
#pragma unroll
    for (int s = 1; s < 64; s <<= 1)
#pragma unroll
      for (int e = 0; e < NEXP; ++e) acc[e] += __shfl_xor(acc[e], s);
    if (lane == 0) {
      float lg[NEXP];
#pragma unroll
      for (int e = 0; e < NEXP; ++e) lg[e] = acc[e] + rbias[e];
      float mx = lg[0]; int am = 0;
#pragma unroll
      for (int e = 1; e < NEXP; ++e) if (lg[e] > mx) { mx = lg[e]; am = e; }
      float p[NEXP]; float se = 0.f;
#pragma unroll
      for (int e = 0; e < NEXP; ++e) { p[e] = __expf(lg[e] - mx); se += p[e]; }
      float inv = 1.f / se;
#pragma unroll
      for (int e = 0; e < NEXP; ++e) { p[e] *= inv; atomicAdd(&sprob[e], p[e]); }
      sel[tok] = am;
      gate[tok] = p[am];
      atomicAdd(&scnt[am], 1);
    }
    __syncthreads();
    if (t < NEXP) {
      pprob[rblk * NEXP + t] = sprob[t];
      pcnt[rblk * NEXP + t] = scnt[t];
    }
  }
}

// ---------------- reduce partials: counts, offsets, tile maps, aux loss ----------------
__global__ void reduce_kernel(const float* __restrict__ pprob, const int* __restrict__ pcnt,
                              int nb, int* __restrict__ meta, float* __restrict__ loss_out) {
  __shared__ float fred[256];
  __shared__ int ired[256];
  int t = threadIdx.x;
  int e = t & 7, i0 = t >> 3;
  float fs = 0.f; int is = 0;
  for (int i = i0; i < nb; i += 32) { fs += pprob[i * 8 + e]; is += pcnt[i * 8 + e]; }
  fred[t] = fs; ired[t] = is;
  __syncthreads();
  if (t < NEXP) {
    float tp = 0.f; int tc = 0;
    for (int j = 0; j < 32; ++j) { tp += fred[j * 8 + t]; tc += ired[j * 8 + t]; }
    meta[t] = tc;        // counts
    fred[t] = tp;
    meta[16 + t] = 0;    // cursors
  }
  __syncthreads();
  if (t == 0) {
    int off = 0; float loss = 0.f; int s1 = 0, s2 = 0;
    for (int q = 0; q < NEXP; ++q) {
      int c = meta[q];
      meta[8 + q] = off;                       // offsets
      int nt1 = (c + 255) >> 8;
      for (int m = 0; m < nt1; ++m) meta[32 + s1++] = (q << 16) | m;
      int nt2 = (c + 127) >> 7;
      for (int m = 0; m < nt2; ++m) meta[96 + s2++] = (q << 16) | m;
      off += c;
      loss += (fred[q] / (float)TOKENS) * ((float)c / (float)TOKENS);
    }
    meta[24] = s1;                             // nslot (BM=256)
    meta[25] = s2;                             // nslot (BM=128)
    *loss_out = loss * (float)NEXP * 0.01f;
  }
}

// ---------------- scatter token indices by expert ----------------
__global__ void scatter_kernel(const int* __restrict__ sel, int* __restrict__ meta,
                               int* __restrict__ idxl) {
  int tok = blockIdx.x * 256 + threadIdx.x;
  int lane = threadIdx.x & 63;
  int e = sel[tok];
  const int* offsets = meta + 8;
  int* cursors = meta + 16;
#pragma unroll
  for (int ex = 0; ex < NEXP; ++ex) {
    unsigned long long mask = __ballot(e == ex);
    if (e == ex) {
      int leader = __ffsll(mask) - 1;
      int total = __popcll(mask);
      int rank = __popcll(mask & ((1ull << lane) - 1ull));
      int base = 0;
      if (lane == leader) base = atomicAdd(&cursors[ex], total);
      base = __shfl(base, leader);
      idxl[offsets[ex] + base + rank] = tok;
    }
  }
}

// ======== shared GEMM core (R17-proven): 256x256 tile, BK=32, 8 waves, 4-buf depth-3 ========
#define STG(Q, KT) do {                                                      \
    int _kb = (KT) * 32;                                                     \
    gl_lds16(apA0 + _kb, L + (Q) * 16384 + wave * 512);                      \
    gl_lds16(apA1 + _kb, L + (Q) * 16384 + 4096 + wave * 512);               \
    gl_lds16(bpB0 + _kb, L + (Q) * 16384 + 8192 + wave * 512);               \
    gl_lds16(bpB1 + _kb, L + (Q) * 16384 + 12288 + wave * 512);              \
  } while (0)

#define CMP(Q) do {                                                          \
    const bf16_t* Ab = L + (Q) * 16384;                                      \
    const bf16_t* Bb = Ab + 8192;                                            \
    bf16x8 bv[4];                                                            \
    _Pragma("unroll")                                                        \
    for (int n = 0; n < 4; ++n)                                              \
      bv[n] = *(const bf16x8*)&Bb[(wcol * 64 + n * 16 + l15) * 32 + ks];     \
    __builtin_amdgcn_s_setprio(1);                                           \
    _Pragma("unroll")                                                        \
    for (int m = 0; m < 8; ++m) {                                            \
      bf16x8 af = *(const bf16x8*)&Ab[(wrow * 128 + m * 16 + l15) * 32 + ks];\
      _Pragma("unroll")                                                      \
      for (int n = 0; n < 4; ++n)                                            \
        acc[m][n] = __builtin_amdgcn_mfma_f32_16x16x32_bf16(af, bv[n], acc[m][n], 0, 0, 0); \
    }                                                                        \
    __builtin_amdgcn_s_setprio(0);                                           \
  } while (0)

#define PIPE(NT) do {                                                        \
    STG(0, 0); STG(1, 1); STG(2, 2);                                         \
    pwait<8>();                                                              \
    _Pragma("unroll 1")                                                      \
    for (int kt = 0; kt < (NT) - 4; kt += 4) {                               \
      STG(3, kt + 3); CMP(0); pwait<8>();                                    \
      STG(0, kt + 4); CMP(1); pwait<8>();                                    \
      STG(1, kt + 5); CMP(2); pwait<8>();                                    \
      STG(2, kt + 6); CMP(3); pwait<8>();                                    \
    }                                                                        \
    STG(3, (NT) - 1); CMP(0); pwait<8>();                                    \
    CMP(1); pwait<4>();                                                      \
    CMP(2); pwait<0>();                                                      \
    CMP(3);                                                                  \
  } while (0)

// ---------------- GEMM1 (+ fused w2 transpose blocks): 256x256 ----------------
#define G1_NWG 640    // 40 slots x 16 n-tiles
#define W2_NBLK 4096  // w2 transpose tiles (128x64), 512 thr

__global__ __launch_bounds__(512, 2) void gemm1_kernel(
    const bf16_t* __restrict__ xb, const bf16_t* __restrict__ w1t,
    const float* __restrict__ b1, const int* __restrict__ idxl,
    const int* __restrict__ meta, bf16_t* __restrict__ h,
    const float* __restrict__ w2, bf16_t* __restrict__ w2t) {
  __shared__ __align__(16) char smemraw[131072];  // 128 KB union
  int f = blockIdx.x;
  int t = threadIdx.x;

  if (f >= G1_NWG) {
    // ---- fused w2 transpose: [E][H=4096][D=1024] -> [E][D][H], tile 128x64 ----
    float (*tile)[65] = (float(*)[65])smemraw;
    int tb = f - G1_NWG;                          // 0..4095
    int e = tb >> 9, xb_ = tb & 511;              // 512 tiles/expert: 32 rt x 16 ct
    const float* src = w2 + (size_t)e * HID * DIM;
    bf16_t* dst = w2t + (size_t)e * HID * DIM;
    int rt = xb_ >> 4, ct = xb_ & 15;
    int rb = rt * 128, cb = ct * 64;
    int r = t >> 2, cq = (t & 3) * 16;
#pragma unroll
    for (int j = 0; j < 16; j += 4) {
      float4 v = *(const float4*)(src + (size_t)(rb + r) * DIM + cb + cq + j);
      tile[r][cq + j + 0] = v.x; tile[r][cq + j + 1] = v.y;
      tile[r][cq + j + 2] = v.z; tile[r][cq + j + 3] = v.w;
    }
    __syncthreads();
    int oc = t >> 3, orr = (t & 7) * 16;
    ushort_t tmp[16];
#pragma unroll
    for (int j = 0; j < 16; ++j) {
      bf16_t b = (bf16_t)tile[orr + j][oc];
      tmp[j] = __builtin_bit_cast(ushort_t, b);
    }
    uint4* dp = (uint4*)(dst + (size_t)(cb + oc) * HID + rb + orr);
    dp[0] = ((uint4*)tmp)[0];
    dp[1] = ((uint4*)tmp)[1];
    return;
  }

  // ---- GEMM1 block: 256x256 ----
  bf16_t* L = (bf16_t*)smemraw;
  int lf = xcd_chunk(f, G1_NWG);
  int slot = lf % 40, nt = lf / 40;
  if (slot >= meta[24]) return;
  int tm = meta[32 + slot];
  int e = tm >> 16, mt = tm & 0xffff;
  int cnt = meta[e];
  int off = meta[8 + e];
  int mBase = mt * 256;
  int nBase = nt * 256;
  int lane = t & 63, wave = t >> 6;  // 8 waves
  int l15 = lane & 15, g = lane >> 4;
  int wrow = wave >> 2, wcol = wave & 3;  // wave tile 128x64
  int ks = (g ^ (l15 & 3)) * 8;
  f32x4 acc[8][4];
#pragma unroll
  for (int m = 0; m < 8; ++m)
#pragma unroll
    for (int n = 0; n < 4; ++n) acc[m][n] = (f32x4){0.f, 0.f, 0.f, 0.f};

  int srow = t >> 2;                       // 0..127
  int koff = ((t & 3) ^ (srow & 3)) * 8;
  int c1 = cnt - 1;
  int sA0 = mBase + srow; sA0 = sA0 < c1 ? sA0 : c1;
  int sA1 = mBase + 128 + srow; sA1 = sA1 < c1 ? sA1 : c1;
  const bf16_t* apA0 = xb + (size_t)idxl[off + sA0] * DIM + koff;
  const bf16_t* apA1 = xb + (size_t)idxl[off + sA1] * DIM + koff;
  const bf16_t* wb = w1t + (size_t)e * HID * DIM;
  const bf16_t* bpB0 = wb + (size_t)(nBase + srow) * DIM + koff;
  const bf16_t* bpB1 = wb + (size_t)(nBase + 128 + srow) * DIM + koff;

  PIPE(32);   // K = 1024

  float bias[4];
#pragma unroll
  for (int n = 0; n < 4; ++n) bias[n] = b1[e * HID + nBase + wcol * 64 + n * 16 + l15];
#pragma unroll
  for (int m = 0; m < 8; ++m) {
    int rb0 = mBase + wrow * 128 + m * 16 + g * 4;
#pragma unroll
    for (int j = 0; j < 4; ++j) {
      int r = rb0 + j;
      if (r < cnt) {
        bf16_t* hp = h + (size_t)(off + r) * HID + nBase + wcol * 64 + l15;
#pragma unroll
        for (int n = 0; n < 4; ++n)
          hp[n * 16] = (bf16_t)gelu_fast(acc[m][n][j] + bias[n]);
      }
    }
  }
}

// ---------------- GEMM2 (R17-proven): 256x256, depth-3 ----------------
__global__ __launch_bounds__(512, 2) void gemm2_kernel(
    const bf16_t* __restrict__ h, const bf16_t* __restrict__ w2t,
    const float* __restrict__ b2, const int* __restrict__ idxl,
    const float* __restrict__ gate, const int* __restrict__ meta,
    float* __restrict__ out) {
  __shared__ bf16_t L[65536];  // 128 KB
  int S = gridDim.x;
  int f = blockIdx.y * S + blockIdx.x;
  int lf = xcd_chunk(f, S * gridDim.y);
  int slot = lf % S, nt = lf / S;
  if (slot >= meta[24]) return;
  int tm = meta[32 + slot];
  int e = tm >> 16, mt = tm & 0xffff;
  int cnt = meta[e];
  int off = meta[8 + e];
  int mBase = mt * 256;
  int nBase = nt * 256;
  int t = threadIdx.x, lane = t & 63, wave = t >> 6;  // 8 waves
  int l15 = lane & 15, g = lane >> 4;
  int wrow = wave >> 2, wcol = wave & 3;  // wave tile 128x64
  int ks = (g ^ (l15 & 3)) * 8;
  f32x4 acc[8][4];
#pragma unroll
  for (int m = 0; m < 8; ++m)
#pragma unroll
    for (int n = 0; n < 4; ++n) acc[m][n] = (f32x4){0.f, 0.f, 0.f, 0.f};

  int srow = t >> 2;
  int koff = ((t & 3) ^ (srow & 3)) * 8;
  int c1 = cnt - 1;
  int sA0 = mBase + srow; sA0 = sA0 < c1 ? sA0 : c1;
  int sA1 = mBase + 128 + srow; sA1 = sA1 < c1 ? sA1 : c1;
  const bf16_t* apA0 = h + (size_t)(off + sA0) * HID + koff;
  const bf16_t* apA1 = h + (size_t)(off + sA1) * HID + koff;
  const bf16_t* wb = w2t + (size_t)e * DIM * HID;
  const bf16_t* bpB0 = wb + (size_t)(nBase + srow) * HID + koff;
  const bf16_t* bpB1 = wb + (size_t)(nBase + 128 + srow) * HID + koff;

  PIPE(128);  // K = 4096

  float bias[4];
#pragma unroll
  for (int n = 0; n < 4; ++n) bias[n] = b2[e * DIM + nBase + wcol * 64 + n * 16 + l15];
#pragma unroll
  for (int m = 0; m < 8; ++m) {
    int rb0 = mBase + wrow * 128 + m * 16 + g * 4;
#pragma unroll
    for (int j = 0; j < 4; ++j) {
      int r = rb0 + j;
      if (r < cnt) {
        int tok = idxl[off + r];
        float gg = gate[tok];
        float* op = out + (size_t)tok * DIM + nBase + wcol * 64 + l15;
#pragma unroll
        for (int n = 0; n < 4; ++n)
          op[n * 16] = gg * (acc[m][n][j] + bias[n]);
      }
    }
  }
}

extern "C" void kernel_launch(void* const* d_in, const int* in_sizes, int n_in,
                              void* d_out, int out_size, void* d_ws, size_t ws_size,
                              hipStream_t stream) {
  const float* hs = (const float*)d_in[0];
  const float* rw = (const float*)d_in[1];
  const float* rb = (const float*)d_in[2];
  const float* w1 = (const float*)d_in[3];
  const float* b1 = (const float*)d_in[4];
  const float* w2 = (const float*)d_in[5];
  const float* b2 = (const float*)d_in[6];
  float* out = (float*)d_out;
  char* ws = (char*)d_ws;

  // workspace layout (bytes)
  bf16_t* xb   = (bf16_t*)(ws + 0);            // 8192*1024*2       = 16,777,216
  bf16_t* w1t  = (bf16_t*)(ws + 16777216);     // 8*4096*1024*2     = 67,108,864
  bf16_t* w2t  = (bf16_t*)(ws + 83886080);     // 8*1024*4096*2     = 67,108,864
  bf16_t* hbuf = (bf16_t*)(ws + 150994944);    // (8192+256)*4096*2
  int*   sel   = (int*)  (ws + 220200960);
  float* gate  = (float*)(ws + 220233728);
  int*   idxl  = (int*)  (ws + 220266496);
  float* pprob = (float*)(ws + 220299264);
  int*   pcnt  = (int*)  (ws + 220364800);
  int*   meta  = (int*)  (ws + 220430336);     // 256 ints

  prep_kernel<<<5120, 512, 0, stream>>>(w1, w1t, hs, rw, rb, xb,
                                        sel, gate, pprob, pcnt);
  reduce_kernel<<<1, 256, 0, stream>>>(pprob, pcnt, 1024, meta, out + (out_size - 1));
  scatter_kernel<<<32, 256, 0, stream>>>(sel, meta, idxl);
  gemm1_kernel<<<G1_NWG + W2_NBLK, 512, 0, stream>>>(xb, w1t, b1, idxl, meta, hbuf,
                                                     w2, w2t);
  gemm2_kernel<<<dim3(40, 4), 512, 0, stream>>>(hbuf, w2t, b2, idxl, gate, meta, out);
}